// Round 17
// baseline (806.531 us; speedup 1.0000x reference)
//
#include <hip/hip_runtime.h>

#define B  4
#define T  2048
#define D  1024
#define NH 16
#define DH 64
#define MROWS (B*T)   // 8192

typedef __attribute__((ext_vector_type(8))) short bf16x8;
typedef __attribute__((ext_vector_type(4))) float f32x4;
typedef __attribute__((ext_vector_type(4))) unsigned short u16x4;
typedef __attribute__((address_space(1))) const void gvoid;
typedef __attribute__((address_space(3))) void lvoid;

#define C_EXP 0.18033688011112042f   // 0.125 * log2(e)
// V-tile swizzle: must spread when dh = 4*lq+j (write) AND dh = dt*16+lq (read)
#define VSWZ(dh) (((((dh) ^ ((dh) >> 2)) & 7)) << 4)

__device__ inline unsigned short f2bf(float f) {
    union { float f; unsigned int u; } v; v.f = f;
    unsigned int r = v.u + 0x7fff + ((v.u >> 16) & 1);   // RNE
    return (unsigned short)(r >> 16);
}
__device__ inline float bf2f(unsigned short u) {
    union { unsigned int u; float f; } v; v.u = ((unsigned int)u) << 16;
    return v.f;
}
__device__ inline float exp2_fast(float x) {
    float r;
    asm("v_exp_f32 %0, %1" : "=v"(r) : "v"(x));   // D = 2^S0
    return r;
}

// ---------------------------------------------------------------------------
// Split fp32 array into bf16 hi + bf16 lo (lo = bf16(x - hi)).
// ---------------------------------------------------------------------------
__global__ __launch_bounds__(256)
void split_f32(const float* __restrict__ in, unsigned short* __restrict__ hi,
               unsigned short* __restrict__ lo, int n4) {
    for (int i = blockIdx.x * 256 + threadIdx.x; i < n4; i += gridDim.x * 256) {
        const float4 v = ((const float4*)in)[i];
        ushort4 h, l;
        h.x = f2bf(v.x); l.x = f2bf(v.x - bf2f(h.x));
        h.y = f2bf(v.y); l.y = f2bf(v.y - bf2f(h.y));
        h.z = f2bf(v.z); l.z = f2bf(v.z - bf2f(h.z));
        h.w = f2bf(v.w); l.w = f2bf(v.w - bf2f(h.w));
        ((ushort4*)hi)[i] = h;
        ((ushort4*)lo)[i] = l;
    }
}

// ---------------------------------------------------------------------------
// W (K x N fp32) -> MFMA-fragment-major bf16 hi/lo (one contiguous 1KB block
// per 16x32 B-fragment; lane l supplies W[kt*32+(l>>4)*8 .. +8][nt*16+(l&15)]).
// ---------------------------------------------------------------------------
__global__ __launch_bounds__(256)
void split_frag(const float* __restrict__ Wm, unsigned short* __restrict__ fh,
                unsigned short* __restrict__ fl, int K, int N) {
    const int l   = threadIdx.x & 63;
    const int nt  = blockIdx.x * 4 + (threadIdx.x >> 6);
    const int kt  = blockIdx.y;
    const int NKT = K / 32;
    const int n   = nt * 16 + (l & 15);
    const int k0  = kt * 32 + (l >> 4) * 8;
    bf16x8 hv, lv;
    #pragma unroll
    for (int j = 0; j < 8; ++j) {
        const float v = Wm[(size_t)(k0 + j) * N + n];
        const unsigned short h = f2bf(v);
        hv[j] = (short)h;
        lv[j] = (short)f2bf(v - bf2f(h));
    }
    const size_t o = ((size_t)nt * NKT + kt) * 512 + (size_t)l * 8;
    *(bf16x8*)&fh[o] = hv;
    *(bf16x8*)&fl[o] = lv;
}

// ---------------------------------------------------------------------------
// Split-bf16 MFMA GEMM, direct-global B with REGISTER DOUBLE-BUFFER:
// B fragments for K-tile kt+1 are loaded into the alternate register set
// (statically named b0*/b1*, K-loop unrolled by 2) while MFMAs consume the
// current set -- L2/L3 B-load latency (~500cy) hides under a full K-tile
// (~1800cy). A ~ Ahi+Alo staged in LDS (gload_lds dbuf, pre-swizzled src).
// 128x128 tile, 4 waves, 32 KB LDS, 3 blocks/CU.
// ---------------------------------------------------------------------------
#define GEMM_PHASE(KT, BHC, BLC, BHN, BLN)                                          \
    {                                                                               \
        const int kt_ = (KT);                                                       \
        if (kt_ + 1 < NKT) {                                                        \
            _Pragma("unroll")                                                       \
            for (int n = 0; n < 4; ++n) {                                           \
                BHN[n] = *(const bf16x8*)&bhBase[((size_t)n * NKT + kt_ + 1) * 512];\
                BLN[n] = *(const bf16x8*)&blBase[((size_t)n * NKT + kt_ + 1) * 512];\
            }                                                                       \
            _Pragma("unroll")                                                       \
            for (int i = 0; i < 4; ++i)                                             \
                __builtin_amdgcn_global_load_lds(                                   \
                    (gvoid*)(aPtr + (size_t)i * 8 * K + (kt_ + 1) * 32),            \
                    (lvoid*)&As[cur ^ 1][(w * 32 + i * 8) * 128], 16, 0, 0);        \
        }                                                                           \
        bf16x8 ah[4], al[4];                                                        \
        _Pragma("unroll")                                                           \
        for (int m = 0; m < 4; ++m) {                                               \
            const int row = wm * 64 + m * 16 + lq;                                  \
            const int sw  = row & 7;                                                \
            ah[m] = *(const bf16x8*)&As[cur][row * 128 + ((lk ^ sw) << 4)];         \
            al[m] = *(const bf16x8*)&As[cur][row * 128 + (((4 + lk) ^ sw) << 4)];   \
        }                                                                           \
        __builtin_amdgcn_s_setprio(1);                                              \
        _Pragma("unroll")                                                           \
        for (int n = 0; n < 4; ++n)                                                 \
            _Pragma("unroll")                                                       \
            for (int m = 0; m < 4; ++m) {                                           \
                acc[m][n] = __builtin_amdgcn_mfma_f32_16x16x32_bf16(ah[m], BHC[n], acc[m][n], 0, 0, 0); \
                acc[m][n] = __builtin_amdgcn_mfma_f32_16x16x32_bf16(ah[m], BLC[n], acc[m][n], 0, 0, 0); \
                acc[m][n] = __builtin_amdgcn_mfma_f32_16x16x32_bf16(al[m], BHC[n], acc[m][n], 0, 0, 0); \
            }                                                                       \
        __builtin_amdgcn_s_setprio(0);                                              \
        __syncthreads();                                                            \
        cur ^= 1;                                                                   \
    }

template<bool OUT_BF16>
__global__ __launch_bounds__(256, 3)
void gemm_bdir(const unsigned short* __restrict__ Ahi, const unsigned short* __restrict__ Alo,
               const unsigned short* __restrict__ Bfh, const unsigned short* __restrict__ Bfl,
               void* __restrict__ Cout, int M, int N, int K) {
    __shared__ unsigned char As[2][128 * 128];   // 128 rows x (hi 64B | lo 64B)
    const int tid  = threadIdx.x;
    const int w    = tid >> 6;        // 0..3
    const int lane = tid & 63;
    const int lq   = lane & 15;
    const int lk   = lane >> 4;
    const int wm   = w >> 1;          // 0..1 -> 64-row band
    const int wn   = w & 1;           // 0..1 -> 64-col band
    const int NKT  = K / 32;

    // XCD-aware bijective swizzle (nwg % 8 == 0 for both launches).
    const int gx  = gridDim.x;
    const int nwg = gx * gridDim.y;
    int lin = blockIdx.y * gx + blockIdx.x;
    lin = (lin & 7) * (nwg >> 3) + (lin >> 3);
    const int bm = (lin / gx) * 128;
    const int bn = (lin % gx) * 128;

    // pre-swizzled A staging source (verified R8 pattern)
    const int srow   = lane >> 3;
    const int sidx   = (lane & 7) ^ srow;
    const int shalf  = sidx >> 2;
    const int schunk = sidx & 3;
    const unsigned short* aPtr = (shalf ? Alo : Ahi) + (size_t)(bm + w * 32 + srow) * K + schunk * 8;

    // per-wave B fragment bases (fragment-major layout)
    const unsigned short* bhBase = Bfh + ((size_t)(bn / 16 + wn * 4) * NKT) * 512 + (size_t)lane * 8;
    const unsigned short* blBase = Bfl + ((size_t)(bn / 16 + wn * 4) * NKT) * 512 + (size_t)lane * 8;

    f32x4 acc[4][4];
    #pragma unroll
    for (int m = 0; m < 4; ++m)
        #pragma unroll
        for (int n = 0; n < 4; ++n) acc[m][n] = f32x4{0.f, 0.f, 0.f, 0.f};

    bf16x8 b0h[4], b0l[4], b1h[4], b1l[4];

    // ---- prologue: B frags for kt=0 + stage A K-tile 0 into buffer 0 ----
    #pragma unroll
    for (int n = 0; n < 4; ++n) {
        b0h[n] = *(const bf16x8*)&bhBase[((size_t)n * NKT) * 512];
        b0l[n] = *(const bf16x8*)&blBase[((size_t)n * NKT) * 512];
    }
    #pragma unroll
    for (int i = 0; i < 4; ++i)
        __builtin_amdgcn_global_load_lds((gvoid*)(aPtr + (size_t)i * 8 * K),
                                         (lvoid*)&As[0][(w * 32 + i * 8) * 128], 16, 0, 0);
    __syncthreads();

    int cur = 0;
    for (int kt = 0; kt < NKT; kt += 2) {
        GEMM_PHASE(kt,     b0h, b0l, b1h, b1l)   // consume set0, prefetch set1
        GEMM_PHASE(kt + 1, b1h, b1l, b0h, b0l)   // consume set1, prefetch set0
    }

    #pragma unroll
    for (int m = 0; m < 4; ++m)
        #pragma unroll
        for (int ri = 0; ri < 4; ++ri) {
            const int row = bm + wm * 64 + m * 16 + lk * 4 + ri;
            #pragma unroll
            for (int n = 0; n < 4; ++n) {
                const int col = bn + wn * 64 + n * 16 + lq;
                if (OUT_BF16)
                    ((unsigned short*)Cout)[(size_t)row * N + col] = f2bf(acc[m][n][ri]);
                else
                    ((float*)Cout)[(size_t)row * N + col] = acc[m][n][ri];
            }
        }
}

// ---------------------------------------------------------------------------
// bf16-MFMA flash attention (unchanged, verified since R8). 8 waves,
// Q-tile 128, KV-tile 64, dbuf K (gload_lds) and V (reg-staged transpose).
// ---------------------------------------------------------------------------
__global__ __launch_bounds__(512)
void attn_mfma(const unsigned short* __restrict__ qkv,
               unsigned short* __restrict__ yhi, unsigned short* __restrict__ ylo) {
    const int bh  = blockIdx.y;
    const int b   = bh / NH;
    const int h   = bh % NH;
    const int qt  = blockIdx.x;           // Q-tile of 128 rows
    const int tid = threadIdx.x;
    const int w    = tid >> 6;            // 0..7
    const int lane = tid & 63;
    const int lq   = lane & 15;
    const int lk   = lane >> 4;

    __shared__ unsigned char Ks [2][64 * 128];  // bf16 [key][dh], swizzled, dbuf
    __shared__ unsigned char Vts[2][64 * 128];  // bf16 [dh][key], VSWZ, dbuf
    __shared__ unsigned char QPs[128 * 128];    // Q tile 128 rows; then P (8 x 2KB)

    // ---- stage Q (bf16 copy, swizzled): 1024 chunks of 16B, 512 thr x 2 ----
    #pragma unroll
    for (int it = 0; it < 2; ++it) {
        const int c   = tid + 512 * it;
        const int row = c >> 3, slot = c & 7;
        const bf16x8 v = *(const bf16x8*)&qkv[(size_t)(b * T + qt * 128 + row) * (3 * D) + h * DH + slot * 8];
        *(bf16x8*)&QPs[row * 128 + ((slot ^ (row & 7)) << 4)] = v;
    }

    // per-lane pre-swizzled source for K global_load_lds (1 instr/wave, 8 rows)
    const int srow   = lane >> 3;
    const int schunk = (lane & 7) ^ srow;
    const unsigned short* kBase = qkv + (size_t)(b * T + w * 8 + srow) * (3 * D) + D + h * DH + schunk * 8;
    // V staging: thread covers keys w*8+lk*2+{0,1}, dh lq*4..lq*4+3
    const unsigned short* vBase = qkv + (size_t)(b * T + w * 8 + lk * 2) * (3 * D) + 2 * D + h * DH + lq * 4;

    // ---- prologue: stage tile 0 into buffer 0 ----
    __builtin_amdgcn_global_load_lds((gvoid*)kBase, (lvoid*)&Ks[0][(w * 8) * 128], 16, 0, 0);
    u16x4 vr[2];
    #pragma unroll
    for (int i = 0; i < 2; ++i)
        vr[i] = *(const u16x4*)(vBase + (size_t)i * (3 * D));
    #pragma unroll
    for (int j = 0; j < 4; ++j) {
        const int dh = lq * 4 + j;
        const unsigned int pk = (unsigned int)vr[0][j] | ((unsigned int)vr[1][j] << 16);
        *(unsigned int*)&Vts[0][(dh * 128 + w * 16 + lk * 4) ^ VSWZ(dh)] = pk;
    }
    __syncthreads();

    // ---- Q fragments (wave w owns rows w*16..w*16+15) ----
    bf16x8 qf[2];
    #pragma unroll
    for (int ks = 0; ks < 2; ++ks) {
        const int row = w * 16 + lq;
        qf[ks] = *(const bf16x8*)&QPs[row * 128 + (((ks * 4 + lk) ^ (row & 7)) << 4)];
    }

    f32x4 o[4];
    #pragma unroll
    for (int dt = 0; dt < 4; ++dt) o[dt] = f32x4{0.f, 0.f, 0.f, 0.f};
    float m_r = -1e30f, l_r = 0.f;

    unsigned char* Pw = &QPs[w * 2048];

    for (int t = 0; t < T / 64; ++t) {
        const int c = t & 1;
        const bool more = (t + 1 < T / 64);
        // ---- issue next-tile staging early (hides under compute) ----
        if (more) {
            const int ktn = (t + 1) * 64;
            __builtin_amdgcn_global_load_lds((gvoid*)(kBase + (size_t)ktn * (3 * D)),
                                             (lvoid*)&Ks[c ^ 1][(w * 8) * 128], 16, 0, 0);
            #pragma unroll
            for (int i = 0; i < 2; ++i)
                vr[i] = *(const u16x4*)(vBase + (size_t)(ktn + i) * (3 * D));
        }

        // ---- S^T = K Q (swapped): lane owns 16 logits of query lq ----
        f32x4 s[4];
        #pragma unroll
        for (int ct = 0; ct < 4; ++ct) s[ct] = f32x4{0.f, 0.f, 0.f, 0.f};
        __builtin_amdgcn_s_setprio(1);
        #pragma unroll
        for (int ks = 0; ks < 2; ++ks) {
            #pragma unroll
            for (int ct = 0; ct < 4; ++ct) {
                const int key = ct * 16 + lq;
                const bf16x8 kf = *(const bf16x8*)&Ks[c][key * 128 + (((ks * 4 + lk) ^ (key & 7)) << 4)];
                s[ct] = __builtin_amdgcn_mfma_f32_16x16x32_bf16(kf, qf[ks], s[ct], 0, 0, 0);
            }
        }
        __builtin_amdgcn_s_setprio(0);

        // ---- online softmax (raw-logit domain) ----
        float v16 = s[0][0];
        #pragma unroll
        for (int ct = 0; ct < 4; ++ct)
            #pragma unroll
            for (int r = 0; r < 4; ++r) v16 = fmaxf(v16, s[ct][r]);
        v16 = fmaxf(v16, __shfl_xor(v16, 16));
        v16 = fmaxf(v16, __shfl_xor(v16, 32));
        if (__any(v16 > m_r)) {
            const float mnew = fmaxf(m_r, v16);
            const float corr = exp2_fast((m_r - mnew) * C_EXP);
            m_r = mnew;
            l_r *= corr;
            float corrO[4];
            #pragma unroll
            for (int r = 0; r < 4; ++r) corrO[r] = __shfl(corr, lk * 4 + r);
            #pragma unroll
            for (int dt = 0; dt < 4; ++dt)
                #pragma unroll
                for (int r = 0; r < 4; ++r) o[dt][r] *= corrO[r];
        }
        const float mC = m_r * C_EXP;
        float p[4][4];
        float tsum = 0.f;
        #pragma unroll
        for (int ct = 0; ct < 4; ++ct)
            #pragma unroll
            for (int r = 0; r < 4; ++r) {
                p[ct][r] = exp2_fast(__builtin_fmaf(s[ct][r], C_EXP, -mC));
                tsum += p[ct][r];
            }
        tsum += __shfl_xor(tsum, 16);
        tsum += __shfl_xor(tsum, 32);
        l_r += tsum;

        // ---- P pack (v_cvt_pk_bf16_f32) + 4x ds_write_b64 ----
        #pragma unroll
        for (int ct = 0; ct < 4; ++ct) {
            uint2 pk2;
            asm("v_cvt_pk_bf16_f32 %0, %1, %2" : "=v"(pk2.x) : "v"(p[ct][0]), "v"(p[ct][1]));
            asm("v_cvt_pk_bf16_f32 %0, %1, %2" : "=v"(pk2.y) : "v"(p[ct][2]), "v"(p[ct][3]));
            *(uint2*)&Pw[(lq * 128 + ct * 32 + lk * 8) ^ ((lq & 7) << 4)] = pk2;
        }
        asm volatile("s_waitcnt lgkmcnt(0)" ::: "memory");
        __builtin_amdgcn_sched_barrier(0);

        // ---- O += P V ----
        __builtin_amdgcn_s_setprio(1);
        #pragma unroll
        for (int ks = 0; ks < 2; ++ks) {
            const bf16x8 pf = *(const bf16x8*)&Pw[(lq * 128 + ks * 64 + lk * 16) ^ ((lq & 7) << 4)];
            #pragma unroll
            for (int dt = 0; dt < 4; ++dt) {
                const int dh = dt * 16 + lq;
                const bf16x8 vf = *(const bf16x8*)&Vts[c][(dh * 128 + ks * 64 + lk * 16) ^ VSWZ(dh)];
                o[dt] = __builtin_amdgcn_mfma_f32_16x16x32_bf16(pf, vf, o[dt], 0, 0, 0);
            }
        }
        __builtin_amdgcn_s_setprio(0);

        // ---- write next V tile into other buffer (vmcnt auto-waited) ----
        if (more) {
            #pragma unroll
            for (int j = 0; j < 4; ++j) {
                const int dh = lq * 4 + j;
                const unsigned int pk = (unsigned int)vr[0][j] | ((unsigned int)vr[1][j] << 16);
                *(unsigned int*)&Vts[c ^ 1][(dh * 128 + w * 16 + lk * 4) ^ VSWZ(dh)] = pk;
            }
        }
        __syncthreads();   // one barrier per tile
    }

    // ---- epilogue: O/l -> y hi/lo bf16 ----
    const float inv = 1.0f / l_r;
    float invO[4];
    #pragma unroll
    for (int r = 0; r < 4; ++r) invO[r] = __shfl(inv, lk * 4 + r);
    #pragma unroll
    for (int r = 0; r < 4; ++r) {
        const int row = qt * 128 + w * 16 + lk * 4 + r;
        const size_t base = (size_t)(b * T + row) * D + h * DH;
        #pragma unroll
        for (int dt = 0; dt < 4; ++dt) {
            const float val = o[dt][r] * invO[r];
            const unsigned short hv = f2bf(val);
            yhi[base + dt * 16 + lq] = hv;
            ylo[base + dt * 16 + lq] = f2bf(val - bf2f(hv));
        }
    }
}

// ---------------------------------------------------------------------------
extern "C" void kernel_launch(void* const* d_in, const int* in_sizes, int n_in,
                              void* d_out, int out_size, void* d_ws, size_t ws_size,
                              hipStream_t stream) {
    const float* x     = (const float*)d_in[0];
    const float* w_qkv = (const float*)d_in[1];
    const float* w_out = (const float*)d_in[2];

    unsigned short* Xhi = (unsigned short*)d_ws;              // M*D (reused as Yhi)
    unsigned short* Xlo = Xhi + (size_t)MROWS * D;            // M*D (reused as Ylo)
    unsigned short* Wqh = Xlo + (size_t)MROWS * D;            // 3D*D frag-major
    unsigned short* Wql = Wqh + (size_t)3 * D * D;
    unsigned short* Woh = Wql + (size_t)3 * D * D;            // D*D frag-major
    unsigned short* Wol = Woh + (size_t)D * D;
    unsigned short* QKV = Wol + (size_t)D * D;                // M*3D bf16

    split_f32<<<2048, 256, 0, stream>>>(x, Xhi, Xlo, MROWS * D / 4);
    split_frag<<<dim3(3 * D / 64, D / 32), 256, 0, stream>>>(w_qkv, Wqh, Wql, D, 3 * D);
    split_frag<<<dim3(D / 64, D / 32), 256, 0, stream>>>(w_out, Woh, Wol, D, D);

    // QKV: 24x64 = 1536 blocks (6 full CU rounds), %8==0
    gemm_bdir<true><<<dim3(3 * D / 128, MROWS / 128), 256, 0, stream>>>(
        Xhi, Xlo, Wqh, Wql, QKV, MROWS, 3 * D, D);

    attn_mfma<<<dim3(T / 128, B * NH), 512, 0, stream>>>(QKV, Xhi, Xlo);

    // out-proj: 8x64 = 512 blocks (2 full CU rounds), %8==0
    gemm_bdir<false><<<dim3(D / 128, MROWS / 128), 256, 0, stream>>>(
        Xhi, Xlo, Woh, Wol, d_out, MROWS, D, D);
}

// Round 20
// 782.163 us; speedup vs baseline: 1.0312x; 1.0312x over previous
//
#include <hip/hip_runtime.h>

#define B  4
#define T  2048
#define D  1024
#define NH 16
#define DH 64
#define MROWS (B*T)   // 8192

typedef __attribute__((ext_vector_type(8))) short bf16x8;
typedef __attribute__((ext_vector_type(4))) float f32x4;
typedef __attribute__((ext_vector_type(4))) unsigned short u16x4;
typedef __attribute__((address_space(1))) const void gvoid;
typedef __attribute__((address_space(3))) void lvoid;

#define C_EXP 0.18033688011112042f   // 0.125 * log2(e)
// V-tile swizzle: must spread when dh = 4*lq+j (write) AND dh = dt*16+lq (read)
#define VSWZ(dh) (((((dh) ^ ((dh) >> 2)) & 7)) << 4)

__device__ inline unsigned short f2bf(float f) {
    union { float f; unsigned int u; } v; v.f = f;
    unsigned int r = v.u + 0x7fff + ((v.u >> 16) & 1);   // RNE
    return (unsigned short)(r >> 16);
}
__device__ inline float bf2f(unsigned short u) {
    union { unsigned int u; float f; } v; v.u = ((unsigned int)u) << 16;
    return v.f;
}
__device__ inline float exp2_fast(float x) {
    float r;
    asm("v_exp_f32 %0, %1" : "=v"(r) : "v"(x));   // D = 2^S0
    return r;
}

// ---------------------------------------------------------------------------
// Split fp32 array into bf16 hi + bf16 lo (lo = bf16(x - hi)).
// ---------------------------------------------------------------------------
__global__ __launch_bounds__(256)
void split_f32(const float* __restrict__ in, unsigned short* __restrict__ hi,
               unsigned short* __restrict__ lo, int n4) {
    for (int i = blockIdx.x * 256 + threadIdx.x; i < n4; i += gridDim.x * 256) {
        const float4 v = ((const float4*)in)[i];
        ushort4 h, l;
        h.x = f2bf(v.x); l.x = f2bf(v.x - bf2f(h.x));
        h.y = f2bf(v.y); l.y = f2bf(v.y - bf2f(h.y));
        h.z = f2bf(v.z); l.z = f2bf(v.z - bf2f(h.z));
        h.w = f2bf(v.w); l.w = f2bf(v.w - bf2f(h.w));
        ((ushort4*)hi)[i] = h;
        ((ushort4*)lo)[i] = l;
    }
}

// ---------------------------------------------------------------------------
// W (K x N fp32) -> MFMA-fragment-major bf16 hi/lo (one contiguous 1KB block
// per 16x32 B-fragment; lane l supplies W[kt*32+(l>>4)*8 .. +8][nt*16+(l&15)]).
// ---------------------------------------------------------------------------
__global__ __launch_bounds__(256)
void split_frag(const float* __restrict__ Wm, unsigned short* __restrict__ fh,
                unsigned short* __restrict__ fl, int K, int N) {
    const int l   = threadIdx.x & 63;
    const int nt  = blockIdx.x * 4 + (threadIdx.x >> 6);
    const int kt  = blockIdx.y;
    const int NKT = K / 32;
    const int n   = nt * 16 + (l & 15);
    const int k0  = kt * 32 + (l >> 4) * 8;
    bf16x8 hv, lv;
    #pragma unroll
    for (int j = 0; j < 8; ++j) {
        const float v = Wm[(size_t)(k0 + j) * N + n];
        const unsigned short h = f2bf(v);
        hv[j] = (short)h;
        lv[j] = (short)f2bf(v - bf2f(h));
    }
    const size_t o = ((size_t)nt * NKT + kt) * 512 + (size_t)l * 8;
    *(bf16x8*)&fh[o] = hv;
    *(bf16x8*)&fl[o] = lv;
}

// ---------------------------------------------------------------------------
// Split-bf16 MFMA GEMM, direct-global B (proven R16 structure): C = A@B,
// 3 MFMA passes (hi*hi + hi*lo + lo*hi). A ~ Ahi+Alo staged in LDS
// (gload_lds dbuf, pre-swizzled source); B fragment-major bf16 loaded
// directly global->VGPR (1 coalesced 1KB load per frag).
// NEW vs R16: (a) column-chunked XCD mapping -- each XCD owns gx/8
// column-tiles so its B working set (1.57 MB at QKV) is L2-RESIDENT,
// cutting B-load latency ~500->~200cy; consecutive j share a row panel
// -> A-panel L2 reuse. (b) 4 blocks/CU (launch_bounds(256,4); VGPR=80
// fits the 128 cap) for more TLP. R17's reg-dbuf REVERTED: it spilled
// (VGPR 84 + WRITE_SIZE 1.39GB scratch signature, 806us).
// ---------------------------------------------------------------------------
template<bool OUT_BF16>
__global__ __launch_bounds__(256, 4)
void gemm_bdir(const unsigned short* __restrict__ Ahi, const unsigned short* __restrict__ Alo,
               const unsigned short* __restrict__ Bfh, const unsigned short* __restrict__ Bfl,
               void* __restrict__ Cout, int M, int N, int K) {
    __shared__ unsigned char As[2][128 * 128];   // 128 rows x (hi 64B | lo 64B)
    const int tid  = threadIdx.x;
    const int w    = tid >> 6;        // 0..3
    const int lane = tid & 63;
    const int lq   = lane & 15;
    const int lk   = lane >> 4;
    const int wm   = w >> 1;          // 0..1 -> 64-row band
    const int wn   = w & 1;           // 0..1 -> 64-col band
    const int NKT  = K / 32;

    // Column-chunked XCD mapping (bijective; needs gx % 8 == 0):
    // XCD cx owns column-tiles [cx*cpx, (cx+1)*cpx); rows iterate outer.
    const int gx  = gridDim.x;
    const int cpx = gx >> 3;                       // col-tiles per XCD
    const int lin = blockIdx.y * gx + blockIdx.x;
    const int cx  = lin & 7;
    const int j   = lin >> 3;
    const int bn  = (cx * cpx + j % cpx) * 128;
    const int bm  = (j / cpx) * 128;

    // pre-swizzled A staging source (verified R8 pattern): lane l -> LDS
    // (row=l>>3, slot=l&7); content = chunk (slot ^ row) of that row.
    const int srow   = lane >> 3;
    const int sidx   = (lane & 7) ^ srow;   // 0..7: 0-3 = hi chunks, 4-7 = lo
    const int shalf  = sidx >> 2;
    const int schunk = sidx & 3;
    const unsigned short* aPtr = (shalf ? Alo : Ahi) + (size_t)(bm + w * 32 + srow) * K + schunk * 8;

    // per-wave B fragment bases (fragment-major layout)
    const unsigned short* bhBase = Bfh + ((size_t)(bn / 16 + wn * 4) * NKT) * 512 + (size_t)lane * 8;
    const unsigned short* blBase = Bfl + ((size_t)(bn / 16 + wn * 4) * NKT) * 512 + (size_t)lane * 8;

    f32x4 acc[4][4];
    #pragma unroll
    for (int m = 0; m < 4; ++m)
        #pragma unroll
        for (int n = 0; n < 4; ++n) acc[m][n] = f32x4{0.f, 0.f, 0.f, 0.f};

    // ---- prologue: stage A K-tile 0 into buffer 0 (4 instr/wave) ----
    #pragma unroll
    for (int i = 0; i < 4; ++i)
        __builtin_amdgcn_global_load_lds((gvoid*)(aPtr + (size_t)i * 8 * K),
                                         (lvoid*)&As[0][(w * 32 + i * 8) * 128], 16, 0, 0);
    __syncthreads();

    int cur = 0;
    for (int kt = 0; kt < NKT; ++kt) {
        // ---- stage next A tile early (hides under this tile's MFMA) ----
        if (kt + 1 < NKT) {
            #pragma unroll
            for (int i = 0; i < 4; ++i)
                __builtin_amdgcn_global_load_lds(
                    (gvoid*)(aPtr + (size_t)i * 8 * K + (kt + 1) * 32),
                    (lvoid*)&As[cur ^ 1][(w * 32 + i * 8) * 128], 16, 0, 0);
        }
        // ---- B fragments: direct coalesced global loads (L2-resident) ----
        bf16x8 bh[4], bl[4];
        #pragma unroll
        for (int n = 0; n < 4; ++n) {
            bh[n] = *(const bf16x8*)&bhBase[((size_t)n * NKT + kt) * 512];
            bl[n] = *(const bf16x8*)&blBase[((size_t)n * NKT + kt) * 512];
        }
        // ---- A fragments from LDS (8 ds_read_b128/wave) ----
        bf16x8 ah[4], al[4];
        #pragma unroll
        for (int m = 0; m < 4; ++m) {
            const int row = wm * 64 + m * 16 + lq;
            const int sw  = row & 7;
            ah[m] = *(const bf16x8*)&As[cur][row * 128 + ((lk ^ sw) << 4)];
            al[m] = *(const bf16x8*)&As[cur][row * 128 + (((4 + lk) ^ sw) << 4)];
        }
        __builtin_amdgcn_s_setprio(1);
        #pragma unroll
        for (int n = 0; n < 4; ++n)
            #pragma unroll
            for (int m = 0; m < 4; ++m) {
                acc[m][n] = __builtin_amdgcn_mfma_f32_16x16x32_bf16(ah[m], bh[n], acc[m][n], 0, 0, 0);
                acc[m][n] = __builtin_amdgcn_mfma_f32_16x16x32_bf16(ah[m], bl[n], acc[m][n], 0, 0, 0);
                acc[m][n] = __builtin_amdgcn_mfma_f32_16x16x32_bf16(al[m], bh[n], acc[m][n], 0, 0, 0);
            }
        __builtin_amdgcn_s_setprio(0);
        __syncthreads();   // drains A staging, protects buf reuse
        cur ^= 1;
    }

    #pragma unroll
    for (int m = 0; m < 4; ++m)
        #pragma unroll
        for (int ri = 0; ri < 4; ++ri) {
            const int row = bm + wm * 64 + m * 16 + lk * 4 + ri;
            #pragma unroll
            for (int n = 0; n < 4; ++n) {
                const int col = bn + wn * 64 + n * 16 + lq;
                if (OUT_BF16)
                    ((unsigned short*)Cout)[(size_t)row * N + col] = f2bf(acc[m][n][ri]);
                else
                    ((float*)Cout)[(size_t)row * N + col] = acc[m][n][ri];
            }
        }
}

// ---------------------------------------------------------------------------
// bf16-MFMA flash attention (unchanged, verified since R8). 8 waves,
// Q-tile 128, KV-tile 64, dbuf K (gload_lds) and V (reg-staged transpose).
// ---------------------------------------------------------------------------
__global__ __launch_bounds__(512)
void attn_mfma(const unsigned short* __restrict__ qkv,
               unsigned short* __restrict__ yhi, unsigned short* __restrict__ ylo) {
    const int bh  = blockIdx.y;
    const int b   = bh / NH;
    const int h   = bh % NH;
    const int qt  = blockIdx.x;           // Q-tile of 128 rows
    const int tid = threadIdx.x;
    const int w    = tid >> 6;            // 0..7
    const int lane = tid & 63;
    const int lq   = lane & 15;
    const int lk   = lane >> 4;

    __shared__ unsigned char Ks [2][64 * 128];  // bf16 [key][dh], swizzled, dbuf
    __shared__ unsigned char Vts[2][64 * 128];  // bf16 [dh][key], VSWZ, dbuf
    __shared__ unsigned char QPs[128 * 128];    // Q tile 128 rows; then P (8 x 2KB)

    // ---- stage Q (bf16 copy, swizzled): 1024 chunks of 16B, 512 thr x 2 ----
    #pragma unroll
    for (int it = 0; it < 2; ++it) {
        const int c   = tid + 512 * it;
        const int row = c >> 3, slot = c & 7;
        const bf16x8 v = *(const bf16x8*)&qkv[(size_t)(b * T + qt * 128 + row) * (3 * D) + h * DH + slot * 8];
        *(bf16x8*)&QPs[row * 128 + ((slot ^ (row & 7)) << 4)] = v;
    }

    // per-lane pre-swizzled source for K global_load_lds (1 instr/wave, 8 rows)
    const int srow   = lane >> 3;
    const int schunk = (lane & 7) ^ srow;
    const unsigned short* kBase = qkv + (size_t)(b * T + w * 8 + srow) * (3 * D) + D + h * DH + schunk * 8;
    // V staging: thread covers keys w*8+lk*2+{0,1}, dh lq*4..lq*4+3
    const unsigned short* vBase = qkv + (size_t)(b * T + w * 8 + lk * 2) * (3 * D) + 2 * D + h * DH + lq * 4;

    // ---- prologue: stage tile 0 into buffer 0 ----
    __builtin_amdgcn_global_load_lds((gvoid*)kBase, (lvoid*)&Ks[0][(w * 8) * 128], 16, 0, 0);
    u16x4 vr[2];
    #pragma unroll
    for (int i = 0; i < 2; ++i)
        vr[i] = *(const u16x4*)(vBase + (size_t)i * (3 * D));
    #pragma unroll
    for (int j = 0; j < 4; ++j) {
        const int dh = lq * 4 + j;
        const unsigned int pk = (unsigned int)vr[0][j] | ((unsigned int)vr[1][j] << 16);
        *(unsigned int*)&Vts[0][(dh * 128 + w * 16 + lk * 4) ^ VSWZ(dh)] = pk;
    }
    __syncthreads();

    // ---- Q fragments (wave w owns rows w*16..w*16+15) ----
    bf16x8 qf[2];
    #pragma unroll
    for (int ks = 0; ks < 2; ++ks) {
        const int row = w * 16 + lq;
        qf[ks] = *(const bf16x8*)&QPs[row * 128 + (((ks * 4 + lk) ^ (row & 7)) << 4)];
    }

    f32x4 o[4];
    #pragma unroll
    for (int dt = 0; dt < 4; ++dt) o[dt] = f32x4{0.f, 0.f, 0.f, 0.f};
    float m_r = -1e30f, l_r = 0.f;

    unsigned char* Pw = &QPs[w * 2048];

    for (int t = 0; t < T / 64; ++t) {
        const int c = t & 1;
        const bool more = (t + 1 < T / 64);
        // ---- issue next-tile staging early (hides under compute) ----
        if (more) {
            const int ktn = (t + 1) * 64;
            __builtin_amdgcn_global_load_lds((gvoid*)(kBase + (size_t)ktn * (3 * D)),
                                             (lvoid*)&Ks[c ^ 1][(w * 8) * 128], 16, 0, 0);
            #pragma unroll
            for (int i = 0; i < 2; ++i)
                vr[i] = *(const u16x4*)(vBase + (size_t)(ktn + i) * (3 * D));
        }

        // ---- S^T = K Q (swapped): lane owns 16 logits of query lq ----
        f32x4 s[4];
        #pragma unroll
        for (int ct = 0; ct < 4; ++ct) s[ct] = f32x4{0.f, 0.f, 0.f, 0.f};
        __builtin_amdgcn_s_setprio(1);
        #pragma unroll
        for (int ks = 0; ks < 2; ++ks) {
            #pragma unroll
            for (int ct = 0; ct < 4; ++ct) {
                const int key = ct * 16 + lq;
                const bf16x8 kf = *(const bf16x8*)&Ks[c][key * 128 + (((ks * 4 + lk) ^ (key & 7)) << 4)];
                s[ct] = __builtin_amdgcn_mfma_f32_16x16x32_bf16(kf, qf[ks], s[ct], 0, 0, 0);
            }
        }
        __builtin_amdgcn_s_setprio(0);

        // ---- online softmax (raw-logit domain) ----
        float v16 = s[0][0];
        #pragma unroll
        for (int ct = 0; ct < 4; ++ct)
            #pragma unroll
            for (int r = 0; r < 4; ++r) v16 = fmaxf(v16, s[ct][r]);
        v16 = fmaxf(v16, __shfl_xor(v16, 16));
        v16 = fmaxf(v16, __shfl_xor(v16, 32));
        if (__any(v16 > m_r)) {
            const float mnew = fmaxf(m_r, v16);
            const float corr = exp2_fast((m_r - mnew) * C_EXP);
            m_r = mnew;
            l_r *= corr;
            float corrO[4];
            #pragma unroll
            for (int r = 0; r < 4; ++r) corrO[r] = __shfl(corr, lk * 4 + r);
            #pragma unroll
            for (int dt = 0; dt < 4; ++dt)
                #pragma unroll
                for (int r = 0; r < 4; ++r) o[dt][r] *= corrO[r];
        }
        const float mC = m_r * C_EXP;
        float p[4][4];
        float tsum = 0.f;
        #pragma unroll
        for (int ct = 0; ct < 4; ++ct)
            #pragma unroll
            for (int r = 0; r < 4; ++r) {
                p[ct][r] = exp2_fast(__builtin_fmaf(s[ct][r], C_EXP, -mC));
                tsum += p[ct][r];
            }
        tsum += __shfl_xor(tsum, 16);
        tsum += __shfl_xor(tsum, 32);
        l_r += tsum;

        // ---- P pack (v_cvt_pk_bf16_f32) + 4x ds_write_b64 ----
        #pragma unroll
        for (int ct = 0; ct < 4; ++ct) {
            uint2 pk2;
            asm("v_cvt_pk_bf16_f32 %0, %1, %2" : "=v"(pk2.x) : "v"(p[ct][0]), "v"(p[ct][1]));
            asm("v_cvt_pk_bf16_f32 %0, %1, %2" : "=v"(pk2.y) : "v"(p[ct][2]), "v"(p[ct][3]));
            *(uint2*)&Pw[(lq * 128 + ct * 32 + lk * 8) ^ ((lq & 7) << 4)] = pk2;
        }
        asm volatile("s_waitcnt lgkmcnt(0)" ::: "memory");
        __builtin_amdgcn_sched_barrier(0);

        // ---- O += P V ----
        __builtin_amdgcn_s_setprio(1);
        #pragma unroll
        for (int ks = 0; ks < 2; ++ks) {
            const bf16x8 pf = *(const bf16x8*)&Pw[(lq * 128 + ks * 64 + lk * 16) ^ ((lq & 7) << 4)];
            #pragma unroll
            for (int dt = 0; dt < 4; ++dt) {
                const int dh = dt * 16 + lq;
                const bf16x8 vf = *(const bf16x8*)&Vts[c][(dh * 128 + ks * 64 + lk * 16) ^ VSWZ(dh)];
                o[dt] = __builtin_amdgcn_mfma_f32_16x16x32_bf16(pf, vf, o[dt], 0, 0, 0);
            }
        }
        __builtin_amdgcn_s_setprio(0);

        // ---- write next V tile into other buffer (vmcnt auto-waited) ----
        if (more) {
            #pragma unroll
            for (int j = 0; j < 4; ++j) {
                const int dh = lq * 4 + j;
                const unsigned int pk = (unsigned int)vr[0][j] | ((unsigned int)vr[1][j] << 16);
                *(unsigned int*)&Vts[c ^ 1][(dh * 128 + w * 16 + lk * 4) ^ VSWZ(dh)] = pk;
            }
        }
        __syncthreads();   // one barrier per tile
    }

    // ---- epilogue: O/l -> y hi/lo bf16 ----
    const float inv = 1.0f / l_r;
    float invO[4];
    #pragma unroll
    for (int r = 0; r < 4; ++r) invO[r] = __shfl(inv, lk * 4 + r);
    #pragma unroll
    for (int r = 0; r < 4; ++r) {
        const int row = qt * 128 + w * 16 + lk * 4 + r;
        const size_t base = (size_t)(b * T + row) * D + h * DH;
        #pragma unroll
        for (int dt = 0; dt < 4; ++dt) {
            const float val = o[dt][r] * invO[r];
            const unsigned short hv = f2bf(val);
            yhi[base + dt * 16 + lq] = hv;
            ylo[base + dt * 16 + lq] = f2bf(val - bf2f(hv));
        }
    }
}

// ---------------------------------------------------------------------------
extern "C" void kernel_launch(void* const* d_in, const int* in_sizes, int n_in,
                              void* d_out, int out_size, void* d_ws, size_t ws_size,
                              hipStream_t stream) {
    const float* x     = (const float*)d_in[0];
    const float* w_qkv = (const float*)d_in[1];
    const float* w_out = (const float*)d_in[2];

    unsigned short* Xhi = (unsigned short*)d_ws;              // M*D (reused as Yhi)
    unsigned short* Xlo = Xhi + (size_t)MROWS * D;            // M*D (reused as Ylo)
    unsigned short* Wqh = Xlo + (size_t)MROWS * D;            // 3D*D frag-major
    unsigned short* Wql = Wqh + (size_t)3 * D * D;
    unsigned short* Woh = Wql + (size_t)3 * D * D;            // D*D frag-major
    unsigned short* Wol = Woh + (size_t)D * D;
    unsigned short* QKV = Wol + (size_t)D * D;                // M*3D bf16

    split_f32<<<2048, 256, 0, stream>>>(x, Xhi, Xlo, MROWS * D / 4);
    split_frag<<<dim3(3 * D / 64, D / 32), 256, 0, stream>>>(w_qkv, Wqh, Wql, D, 3 * D);
    split_frag<<<dim3(D / 64, D / 32), 256, 0, stream>>>(w_out, Woh, Wol, D, D);

    // QKV: 24x64 = 1536 blocks (gx=24, 24%8==0)
    gemm_bdir<true><<<dim3(3 * D / 128, MROWS / 128), 256, 0, stream>>>(
        Xhi, Xlo, Wqh, Wql, QKV, MROWS, 3 * D, D);

    attn_mfma<<<dim3(T / 128, B * NH), 512, 0, stream>>>(QKV, Xhi, Xlo);

    // out-proj: 8x64 = 512 blocks (gx=8)
    gemm_bdir<false><<<dim3(D / 128, MROWS / 128), 256, 0, stream>>>(
        Xhi, Xlo, Woh, Wol, d_out, MROWS, D, D);
}

// Round 21
// 347.184 us; speedup vs baseline: 2.3231x; 2.2529x over previous
//
#include <hip/hip_runtime.h>

#define B  4
#define T  2048
#define D  1024
#define NH 16
#define DH 64
#define MROWS (B*T)   // 8192

typedef __attribute__((ext_vector_type(8))) short bf16x8;
typedef __attribute__((ext_vector_type(4))) float f32x4;
typedef __attribute__((ext_vector_type(4))) unsigned short u16x4;
typedef __attribute__((address_space(1))) const void gvoid;
typedef __attribute__((address_space(3))) void lvoid;

#define C_EXP 0.18033688011112042f   // 0.125 * log2(e)
// V-tile swizzle: must spread when dh = 4*lq+j (write) AND dh = dt*16+lq (read)
#define VSWZ(dh) (((((dh) ^ ((dh) >> 2)) & 7)) << 4)

__device__ inline unsigned short f2bf(float f) {
    union { float f; unsigned int u; } v; v.f = f;
    unsigned int r = v.u + 0x7fff + ((v.u >> 16) & 1);   // RNE
    return (unsigned short)(r >> 16);
}
__device__ inline float bf2f(unsigned short u) {
    union { unsigned int u; float f; } v; v.u = ((unsigned int)u) << 16;
    return v.f;
}
__device__ inline float exp2_fast(float x) {
    float r;
    asm("v_exp_f32 %0, %1" : "=v"(r) : "v"(x));   // D = 2^S0
    return r;
}

// ---------------------------------------------------------------------------
// Split fp32 array into bf16 hi + bf16 lo (lo = bf16(x - hi)).
// ---------------------------------------------------------------------------
__global__ __launch_bounds__(256)
void split_f32(const float* __restrict__ in, unsigned short* __restrict__ hi,
               unsigned short* __restrict__ lo, int n4) {
    for (int i = blockIdx.x * 256 + threadIdx.x; i < n4; i += gridDim.x * 256) {
        const float4 v = ((const float4*)in)[i];
        ushort4 h, l;
        h.x = f2bf(v.x); l.x = f2bf(v.x - bf2f(h.x));
        h.y = f2bf(v.y); l.y = f2bf(v.y - bf2f(h.y));
        h.z = f2bf(v.z); l.z = f2bf(v.z - bf2f(h.z));
        h.w = f2bf(v.w); l.w = f2bf(v.w - bf2f(h.w));
        ((ushort4*)hi)[i] = h;
        ((ushort4*)lo)[i] = l;
    }
}

// ---------------------------------------------------------------------------
// W (K x N fp32) -> MFMA-fragment-major bf16 hi/lo (one contiguous 1KB block
// per 16x32 B-fragment; lane l supplies W[kt*32+(l>>4)*8 .. +8][nt*16+(l&15)]).
// ---------------------------------------------------------------------------
__global__ __launch_bounds__(256)
void split_frag(const float* __restrict__ Wm, unsigned short* __restrict__ fh,
                unsigned short* __restrict__ fl, int K, int N) {
    const int l   = threadIdx.x & 63;
    const int nt  = blockIdx.x * 4 + (threadIdx.x >> 6);
    const int kt  = blockIdx.y;
    const int NKT = K / 32;
    const int n   = nt * 16 + (l & 15);
    const int k0  = kt * 32 + (l >> 4) * 8;
    bf16x8 hv, lv;
    #pragma unroll
    for (int j = 0; j < 8; ++j) {
        const float v = Wm[(size_t)(k0 + j) * N + n];
        const unsigned short h = f2bf(v);
        hv[j] = (short)h;
        lv[j] = (short)f2bf(v - bf2f(h));
    }
    const size_t o = ((size_t)nt * NKT + kt) * 512 + (size_t)l * 8;
    *(bf16x8*)&fh[o] = hv;
    *(bf16x8*)&fl[o] = lv;
}

// ---------------------------------------------------------------------------
// Split-bf16 MFMA GEMM, direct-global B (R16 structure, measured 343us /
// QKV 145us @ MfmaUtil 50%): C = A@B, 3 MFMA passes (hi*hi+hi*lo+lo*hi).
// A ~ Ahi+Alo staged in LDS (gload_lds dbuf, pre-swizzled source);
// B fragment-major bf16 loaded directly global->VGPR.
// SINGLE change vs R16: column-chunked XCD mapping -- each XCD owns gx/8
// column-tiles so its B working set (1.57 MB at QKV) is L2-RESIDENT
// (~200cy vs ~500cy L3); consecutive j share a row panel (A L2 reuse).
// launch_bounds STAYS (256,3): R20 proved (256,4) spills the accumulators
// (VGPR 64 + WRITE_SIZE 1.22GB scratch signature, 782us).
// ---------------------------------------------------------------------------
template<bool OUT_BF16>
__global__ __launch_bounds__(256, 3)
void gemm_bdir(const unsigned short* __restrict__ Ahi, const unsigned short* __restrict__ Alo,
               const unsigned short* __restrict__ Bfh, const unsigned short* __restrict__ Bfl,
               void* __restrict__ Cout, int M, int N, int K) {
    __shared__ unsigned char As[2][128 * 128];   // 128 rows x (hi 64B | lo 64B)
    const int tid  = threadIdx.x;
    const int w    = tid >> 6;        // 0..3
    const int lane = tid & 63;
    const int lq   = lane & 15;
    const int lk   = lane >> 4;
    const int wm   = w >> 1;          // 0..1 -> 64-row band
    const int wn   = w & 1;           // 0..1 -> 64-col band
    const int NKT  = K / 32;

    // Column-chunked XCD mapping (bijective; needs gx % 8 == 0):
    // XCD cx owns column-tiles [cx*cpx, (cx+1)*cpx); rows iterate outer.
    const int gx  = gridDim.x;
    const int cpx = gx >> 3;                       // col-tiles per XCD
    const int lin = blockIdx.y * gx + blockIdx.x;
    const int cx  = lin & 7;
    const int j   = lin >> 3;
    const int bn  = (cx * cpx + j % cpx) * 128;
    const int bm  = (j / cpx) * 128;

    // pre-swizzled A staging source (verified R8 pattern): lane l -> LDS
    // (row=l>>3, slot=l&7); content = chunk (slot ^ row) of that row.
    const int srow   = lane >> 3;
    const int sidx   = (lane & 7) ^ srow;   // 0..7: 0-3 = hi chunks, 4-7 = lo
    const int shalf  = sidx >> 2;
    const int schunk = sidx & 3;
    const unsigned short* aPtr = (shalf ? Alo : Ahi) + (size_t)(bm + w * 32 + srow) * K + schunk * 8;

    // per-wave B fragment bases (fragment-major layout)
    const unsigned short* bhBase = Bfh + ((size_t)(bn / 16 + wn * 4) * NKT) * 512 + (size_t)lane * 8;
    const unsigned short* blBase = Bfl + ((size_t)(bn / 16 + wn * 4) * NKT) * 512 + (size_t)lane * 8;

    f32x4 acc[4][4];
    #pragma unroll
    for (int m = 0; m < 4; ++m)
        #pragma unroll
        for (int n = 0; n < 4; ++n) acc[m][n] = f32x4{0.f, 0.f, 0.f, 0.f};

    // ---- prologue: stage A K-tile 0 into buffer 0 (4 instr/wave) ----
    #pragma unroll
    for (int i = 0; i < 4; ++i)
        __builtin_amdgcn_global_load_lds((gvoid*)(aPtr + (size_t)i * 8 * K),
                                         (lvoid*)&As[0][(w * 32 + i * 8) * 128], 16, 0, 0);
    __syncthreads();

    int cur = 0;
    for (int kt = 0; kt < NKT; ++kt) {
        // ---- stage next A tile early (hides under this tile's MFMA) ----
        if (kt + 1 < NKT) {
            #pragma unroll
            for (int i = 0; i < 4; ++i)
                __builtin_amdgcn_global_load_lds(
                    (gvoid*)(aPtr + (size_t)i * 8 * K + (kt + 1) * 32),
                    (lvoid*)&As[cur ^ 1][(w * 32 + i * 8) * 128], 16, 0, 0);
        }
        // ---- B fragments: direct coalesced global loads (L2-resident) ----
        bf16x8 bh[4], bl[4];
        #pragma unroll
        for (int n = 0; n < 4; ++n) {
            bh[n] = *(const bf16x8*)&bhBase[((size_t)n * NKT + kt) * 512];
            bl[n] = *(const bf16x8*)&blBase[((size_t)n * NKT + kt) * 512];
        }
        // ---- A fragments from LDS (8 ds_read_b128/wave) ----
        bf16x8 ah[4], al[4];
        #pragma unroll
        for (int m = 0; m < 4; ++m) {
            const int row = wm * 64 + m * 16 + lq;
            const int sw  = row & 7;
            ah[m] = *(const bf16x8*)&As[cur][row * 128 + ((lk ^ sw) << 4)];
            al[m] = *(const bf16x8*)&As[cur][row * 128 + (((4 + lk) ^ sw) << 4)];
        }
        __builtin_amdgcn_s_setprio(1);
        #pragma unroll
        for (int n = 0; n < 4; ++n)
            #pragma unroll
            for (int m = 0; m < 4; ++m) {
                acc[m][n] = __builtin_amdgcn_mfma_f32_16x16x32_bf16(ah[m], bh[n], acc[m][n], 0, 0, 0);
                acc[m][n] = __builtin_amdgcn_mfma_f32_16x16x32_bf16(ah[m], bl[n], acc[m][n], 0, 0, 0);
                acc[m][n] = __builtin_amdgcn_mfma_f32_16x16x32_bf16(al[m], bh[n], acc[m][n], 0, 0, 0);
            }
        __builtin_amdgcn_s_setprio(0);
        __syncthreads();   // drains A staging, protects buf reuse
        cur ^= 1;
    }

    #pragma unroll
    for (int m = 0; m < 4; ++m)
        #pragma unroll
        for (int ri = 0; ri < 4; ++ri) {
            const int row = bm + wm * 64 + m * 16 + lk * 4 + ri;
            #pragma unroll
            for (int n = 0; n < 4; ++n) {
                const int col = bn + wn * 64 + n * 16 + lq;
                if (OUT_BF16)
                    ((unsigned short*)Cout)[(size_t)row * N + col] = f2bf(acc[m][n][ri]);
                else
                    ((float*)Cout)[(size_t)row * N + col] = acc[m][n][ri];
            }
        }
}

// ---------------------------------------------------------------------------
// bf16-MFMA flash attention (unchanged, verified since R8). 8 waves,
// Q-tile 128, KV-tile 64, dbuf K (gload_lds) and V (reg-staged transpose).
// ---------------------------------------------------------------------------
__global__ __launch_bounds__(512)
void attn_mfma(const unsigned short* __restrict__ qkv,
               unsigned short* __restrict__ yhi, unsigned short* __restrict__ ylo) {
    const int bh  = blockIdx.y;
    const int b   = bh / NH;
    const int h   = bh % NH;
    const int qt  = blockIdx.x;           // Q-tile of 128 rows
    const int tid = threadIdx.x;
    const int w    = tid >> 6;            // 0..7
    const int lane = tid & 63;
    const int lq   = lane & 15;
    const int lk   = lane >> 4;

    __shared__ unsigned char Ks [2][64 * 128];  // bf16 [key][dh], swizzled, dbuf
    __shared__ unsigned char Vts[2][64 * 128];  // bf16 [dh][key], VSWZ, dbuf
    __shared__ unsigned char QPs[128 * 128];    // Q tile 128 rows; then P (8 x 2KB)

    // ---- stage Q (bf16 copy, swizzled): 1024 chunks of 16B, 512 thr x 2 ----
    #pragma unroll
    for (int it = 0; it < 2; ++it) {
        const int c   = tid + 512 * it;
        const int row = c >> 3, slot = c & 7;
        const bf16x8 v = *(const bf16x8*)&qkv[(size_t)(b * T + qt * 128 + row) * (3 * D) + h * DH + slot * 8];
        *(bf16x8*)&QPs[row * 128 + ((slot ^ (row & 7)) << 4)] = v;
    }

    // per-lane pre-swizzled source for K global_load_lds (1 instr/wave, 8 rows)
    const int srow   = lane >> 3;
    const int schunk = (lane & 7) ^ srow;
    const unsigned short* kBase = qkv + (size_t)(b * T + w * 8 + srow) * (3 * D) + D + h * DH + schunk * 8;
    // V staging: thread covers keys w*8+lk*2+{0,1}, dh lq*4..lq*4+3
    const unsigned short* vBase = qkv + (size_t)(b * T + w * 8 + lk * 2) * (3 * D) + 2 * D + h * DH + lq * 4;

    // ---- prologue: stage tile 0 into buffer 0 ----
    __builtin_amdgcn_global_load_lds((gvoid*)kBase, (lvoid*)&Ks[0][(w * 8) * 128], 16, 0, 0);
    u16x4 vr[2];
    #pragma unroll
    for (int i = 0; i < 2; ++i)
        vr[i] = *(const u16x4*)(vBase + (size_t)i * (3 * D));
    #pragma unroll
    for (int j = 0; j < 4; ++j) {
        const int dh = lq * 4 + j;
        const unsigned int pk = (unsigned int)vr[0][j] | ((unsigned int)vr[1][j] << 16);
        *(unsigned int*)&Vts[0][(dh * 128 + w * 16 + lk * 4) ^ VSWZ(dh)] = pk;
    }
    __syncthreads();

    // ---- Q fragments (wave w owns rows w*16..w*16+15) ----
    bf16x8 qf[2];
    #pragma unroll
    for (int ks = 0; ks < 2; ++ks) {
        const int row = w * 16 + lq;
        qf[ks] = *(const bf16x8*)&QPs[row * 128 + (((ks * 4 + lk) ^ (row & 7)) << 4)];
    }

    f32x4 o[4];
    #pragma unroll
    for (int dt = 0; dt < 4; ++dt) o[dt] = f32x4{0.f, 0.f, 0.f, 0.f};
    float m_r = -1e30f, l_r = 0.f;

    unsigned char* Pw = &QPs[w * 2048];

    for (int t = 0; t < T / 64; ++t) {
        const int c = t & 1;
        const bool more = (t + 1 < T / 64);
        // ---- issue next-tile staging early (hides under compute) ----
        if (more) {
            const int ktn = (t + 1) * 64;
            __builtin_amdgcn_global_load_lds((gvoid*)(kBase + (size_t)ktn * (3 * D)),
                                             (lvoid*)&Ks[c ^ 1][(w * 8) * 128], 16, 0, 0);
            #pragma unroll
            for (int i = 0; i < 2; ++i)
                vr[i] = *(const u16x4*)(vBase + (size_t)(ktn + i) * (3 * D));
        }

        // ---- S^T = K Q (swapped): lane owns 16 logits of query lq ----
        f32x4 s[4];
        #pragma unroll
        for (int ct = 0; ct < 4; ++ct) s[ct] = f32x4{0.f, 0.f, 0.f, 0.f};
        __builtin_amdgcn_s_setprio(1);
        #pragma unroll
        for (int ks = 0; ks < 2; ++ks) {
            #pragma unroll
            for (int ct = 0; ct < 4; ++ct) {
                const int key = ct * 16 + lq;
                const bf16x8 kf = *(const bf16x8*)&Ks[c][key * 128 + (((ks * 4 + lk) ^ (key & 7)) << 4)];
                s[ct] = __builtin_amdgcn_mfma_f32_16x16x32_bf16(kf, qf[ks], s[ct], 0, 0, 0);
            }
        }
        __builtin_amdgcn_s_setprio(0);

        // ---- online softmax (raw-logit domain) ----
        float v16 = s[0][0];
        #pragma unroll
        for (int ct = 0; ct < 4; ++ct)
            #pragma unroll
            for (int r = 0; r < 4; ++r) v16 = fmaxf(v16, s[ct][r]);
        v16 = fmaxf(v16, __shfl_xor(v16, 16));
        v16 = fmaxf(v16, __shfl_xor(v16, 32));
        if (__any(v16 > m_r)) {
            const float mnew = fmaxf(m_r, v16);
            const float corr = exp2_fast((m_r - mnew) * C_EXP);
            m_r = mnew;
            l_r *= corr;
            float corrO[4];
            #pragma unroll
            for (int r = 0; r < 4; ++r) corrO[r] = __shfl(corr, lk * 4 + r);
            #pragma unroll
            for (int dt = 0; dt < 4; ++dt)
                #pragma unroll
                for (int r = 0; r < 4; ++r) o[dt][r] *= corrO[r];
        }
        const float mC = m_r * C_EXP;
        float p[4][4];
        float tsum = 0.f;
        #pragma unroll
        for (int ct = 0; ct < 4; ++ct)
            #pragma unroll
            for (int r = 0; r < 4; ++r) {
                p[ct][r] = exp2_fast(__builtin_fmaf(s[ct][r], C_EXP, -mC));
                tsum += p[ct][r];
            }
        tsum += __shfl_xor(tsum, 16);
        tsum += __shfl_xor(tsum, 32);
        l_r += tsum;

        // ---- P pack (v_cvt_pk_bf16_f32) + 4x ds_write_b64 ----
        #pragma unroll
        for (int ct = 0; ct < 4; ++ct) {
            uint2 pk2;
            asm("v_cvt_pk_bf16_f32 %0, %1, %2" : "=v"(pk2.x) : "v"(p[ct][0]), "v"(p[ct][1]));
            asm("v_cvt_pk_bf16_f32 %0, %1, %2" : "=v"(pk2.y) : "v"(p[ct][2]), "v"(p[ct][3]));
            *(uint2*)&Pw[(lq * 128 + ct * 32 + lk * 8) ^ ((lq & 7) << 4)] = pk2;
        }
        asm volatile("s_waitcnt lgkmcnt(0)" ::: "memory");
        __builtin_amdgcn_sched_barrier(0);

        // ---- O += P V ----
        __builtin_amdgcn_s_setprio(1);
        #pragma unroll
        for (int ks = 0; ks < 2; ++ks) {
            const bf16x8 pf = *(const bf16x8*)&Pw[(lq * 128 + ks * 64 + lk * 16) ^ ((lq & 7) << 4)];
            #pragma unroll
            for (int dt = 0; dt < 4; ++dt) {
                const int dh = dt * 16 + lq;
                const bf16x8 vf = *(const bf16x8*)&Vts[c][(dh * 128 + ks * 64 + lk * 16) ^ VSWZ(dh)];
                o[dt] = __builtin_amdgcn_mfma_f32_16x16x32_bf16(pf, vf, o[dt], 0, 0, 0);
            }
        }
        __builtin_amdgcn_s_setprio(0);

        // ---- write next V tile into other buffer (vmcnt auto-waited) ----
        if (more) {
            #pragma unroll
            for (int j = 0; j < 4; ++j) {
                const int dh = lq * 4 + j;
                const unsigned int pk = (unsigned int)vr[0][j] | ((unsigned int)vr[1][j] << 16);
                *(unsigned int*)&Vts[c ^ 1][(dh * 128 + w * 16 + lk * 4) ^ VSWZ(dh)] = pk;
            }
        }
        __syncthreads();   // one barrier per tile
    }

    // ---- epilogue: O/l -> y hi/lo bf16 ----
    const float inv = 1.0f / l_r;
    float invO[4];
    #pragma unroll
    for (int r = 0; r < 4; ++r) invO[r] = __shfl(inv, lk * 4 + r);
    #pragma unroll
    for (int r = 0; r < 4; ++r) {
        const int row = qt * 128 + w * 16 + lk * 4 + r;
        const size_t base = (size_t)(b * T + row) * D + h * DH;
        #pragma unroll
        for (int dt = 0; dt < 4; ++dt) {
            const float val = o[dt][r] * invO[r];
            const unsigned short hv = f2bf(val);
            yhi[base + dt * 16 + lq] = hv;
            ylo[base + dt * 16 + lq] = f2bf(val - bf2f(hv));
        }
    }
}

// ---------------------------------------------------------------------------
extern "C" void kernel_launch(void* const* d_in, const int* in_sizes, int n_in,
                              void* d_out, int out_size, void* d_ws, size_t ws_size,
                              hipStream_t stream) {
    const float* x     = (const float*)d_in[0];
    const float* w_qkv = (const float*)d_in[1];
    const float* w_out = (const float*)d_in[2];

    unsigned short* Xhi = (unsigned short*)d_ws;              // M*D (reused as Yhi)
    unsigned short* Xlo = Xhi + (size_t)MROWS * D;            // M*D (reused as Ylo)
    unsigned short* Wqh = Xlo + (size_t)MROWS * D;            // 3D*D frag-major
    unsigned short* Wql = Wqh + (size_t)3 * D * D;
    unsigned short* Woh = Wql + (size_t)3 * D * D;            // D*D frag-major
    unsigned short* Wol = Woh + (size_t)D * D;
    unsigned short* QKV = Wol + (size_t)D * D;                // M*3D bf16

    split_f32<<<2048, 256, 0, stream>>>(x, Xhi, Xlo, MROWS * D / 4);
    split_frag<<<dim3(3 * D / 64, D / 32), 256, 0, stream>>>(w_qkv, Wqh, Wql, D, 3 * D);
    split_frag<<<dim3(D / 64, D / 32), 256, 0, stream>>>(w_out, Woh, Wol, D, D);

    // QKV: 24x64 = 1536 blocks (gx=24, 24%8==0)
    gemm_bdir<true><<<dim3(3 * D / 128, MROWS / 128), 256, 0, stream>>>(
        Xhi, Xlo, Wqh, Wql, QKV, MROWS, 3 * D, D);

    attn_mfma<<<dim3(T / 128, B * NH), 512, 0, stream>>>(QKV, Xhi, Xlo);

    // out-proj: 8x64 = 512 blocks (gx=8)
    gemm_bdir<false><<<dim3(D / 128, MROWS / 128), 256, 0, stream>>>(
        Xhi, Xlo, Woh, Wol, d_out, MROWS, D, D);
}